// Round 6
// baseline (508.179 us; speedup 1.0000x reference)
//
#include <hip/hip_runtime.h>
#include <hip/hip_bf16.h>

// Problem constants (from reference): B=64, C=256, H=64, W=64, EMB=512, NH=4, HD=64.
// Key algebraic fact: K/V sequence length is 1 -> softmax over a size-1 axis == 1.0
// identically, so q / layernorm / wk are dead code. The whole block reduces to:
//   v_in[b]     = cond_emb[b] @ kv_w[C:2C].T + kv_b[C:2C]          (64 x 256)
//   v_row[b]    = v_in[b] @ wv.T + bv,  wv = in_proj_w[2C:3C]      (64 x 256)
//   attn_out[b] = v_row[b] @ out_w.T + out_b                       (64 x 256)
//   y[b,c,h,w]  = x[b,c,h,w] + attn_out[b,c]
// Structural floor: elementwise pass reads+writes 2 * 268 MB -> ~85 us at 6.3 TB/s.
// Timed graph also contains ~2x 1GiB harness poison fills (~330 us) we cannot touch.
//
// History of the add pass (per-iteration decomposition, fills subtracted):
//  R0: 65,536 blocks x 1 float4/thread          -> ~133 us (4.0 TB/s demand)
//  R3: 4,096 blocks x 16 float4 + nt stores     -> 167 us (VGPR=32, serialized) REVERTED
//  R4: 16,384 blocks x 4 float4 named regs      -> ~135 us (== R0: depth is NOT the limiter;
//      HBM-side only ~3.0 TB/s, FETCH~134MB shows half of x L3-hits -> HBM NOT saturated)
//  R5: replicate the structure that measured 6.29 TB/s mixed copy on this chip
//      (learn_hip m13): 2,048 persistent blocks, flat grid-stride float4 loop.
//      (R5 bench was an infra failure — this is the same kernel, resubmitted.)

#define Bc 64
#define Cc 256
#define EMBc 512
#define HWc 4096

typedef float v4f __attribute__((ext_vector_type(4)));

// One block per batch element, 512 threads: 2-way split-K on every GEMV stage.
__global__ __launch_bounds__(512) void attn_vec_kernel(
    const float* __restrict__ cond_emb,   // (B, EMB)
    const float* __restrict__ in_proj_w,  // (3C, C)
    const float* __restrict__ in_proj_b,  // (3C,)
    const float* __restrict__ out_w,      // (C, C)
    const float* __restrict__ out_b,      // (C,)
    const float* __restrict__ kv_w,       // (2C, EMB)
    const float* __restrict__ kv_b,       // (2C,)
    float* __restrict__ attn_out)         // (B, C) scratch
{
    __shared__ float4 s_cond[EMBc / 4];   // 128 float4 = 2 KB
    __shared__ float  s_part[512];        // split-K partials
    __shared__ float4 s_vin[Cc / 4];      // 64 float4
    __shared__ float4 s_vrow[Cc / 4];     // 64 float4

    const int b   = blockIdx.x;
    const int tid = threadIdx.x;
    const int o   = tid & 255;            // output element
    const int h   = tid >> 8;             // K-half: 0 or 1

    // stage cond_emb row (512 floats = 128 float4)
    if (tid < EMBc / 4)
        s_cond[tid] = ((const float4*)(cond_emb + (size_t)b * EMBc))[tid];
    __syncthreads();

    // stage 1: v_in[o] = cond . kv_w[C+o, :] + kv_b[C+o]   (dot-512, split 2x256)
    {
        const float4* wrow = (const float4*)(kv_w + (size_t)(Cc + o) * EMBc) + h * 64;
        const float4* crow = s_cond + h * 64;
        float acc = 0.f;
        #pragma unroll 8
        for (int e = 0; e < 64; ++e) {
            float4 w = wrow[e], c = crow[e];
            acc += w.x * c.x + w.y * c.y + w.z * c.z + w.w * c.w;
        }
        s_part[tid] = acc;
    }
    __syncthreads();
    if (tid < 256)
        ((float*)s_vin)[tid] = s_part[tid] + s_part[tid + 256] + kv_b[Cc + tid];
    __syncthreads();

    // stage 2: v_row[o] = v_in . wv[o, :] + bv[o]   (dot-256, split 2x128)
    {
        const float4* wrow = (const float4*)(in_proj_w + (size_t)(2 * Cc + o) * Cc) + h * 32;
        const float4* crow = s_vin + h * 32;
        float acc = 0.f;
        #pragma unroll 8
        for (int j = 0; j < 32; ++j) {
            float4 w = wrow[j], c = crow[j];
            acc += w.x * c.x + w.y * c.y + w.z * c.z + w.w * c.w;
        }
        s_part[tid] = acc;
    }
    __syncthreads();
    if (tid < 256)
        ((float*)s_vrow)[tid] = s_part[tid] + s_part[tid + 256] + in_proj_b[2 * Cc + tid];
    __syncthreads();

    // stage 3: attn_out[b,o] = v_row . out_w[o, :] + out_b[o]   (dot-256, split 2x128)
    {
        const float4* wrow = (const float4*)(out_w + (size_t)o * Cc) + h * 32;
        const float4* crow = s_vrow + h * 32;
        float acc = 0.f;
        #pragma unroll 8
        for (int i = 0; i < 32; ++i) {
            float4 w = wrow[i], c = crow[i];
            acc += w.x * c.x + w.y * c.y + w.z * c.z + w.w * c.w;
        }
        s_part[tid] = acc;
    }
    __syncthreads();
    if (tid < 256)
        attn_out[(size_t)b * Cc + tid] = s_part[tid] + s_part[tid + 256] + out_b[tid];
}

// y = x + attn_out[b,c].
// m13-replica structure (6.29 TB/s measured float4 copy): 2,048 persistent
// blocks x 256 threads, flat grid-stride loop, 32 iterations/thread.
// The addend attn_out[idx>>10] is wave-uniform (all 64 lanes in a wave sit
// inside one 1024-float4 plane chunk) -> L1-broadcast load, negligible bytes.
// Plain stores (R3 showed nt stores don't improve x L3 residency here).
__global__ __launch_bounds__(256) void add_broadcast_kernel(
    const v4f* __restrict__ x4,
    const float* __restrict__ attn_out,
    v4f* __restrict__ y4)
{
    const size_t stride = (size_t)2048 * 256;             // grid * block
    size_t idx = (size_t)blockIdx.x * 256 + threadIdx.x;  // float4 index

    #pragma unroll 4
    for (int i = 0; i < 32; ++i) {
        const float a = attn_out[idx >> 10];   // plane = idx4 / 1024, wave-uniform
        v4f v = x4[idx];
        y4[idx] = v + a;
        idx += stride;
    }
}

extern "C" void kernel_launch(void* const* d_in, const int* in_sizes, int n_in,
                              void* d_out, int out_size, void* d_ws, size_t ws_size,
                              hipStream_t stream) {
    const float* x         = (const float*)d_in[0];
    const float* cond_emb  = (const float*)d_in[1];
    // d_in[2] ln_gamma, d_in[3] ln_beta: dead (only feed q, which softmax erases)
    const float* in_proj_w = (const float*)d_in[4];
    const float* in_proj_b = (const float*)d_in[5];
    const float* out_w     = (const float*)d_in[6];
    const float* out_b     = (const float*)d_in[7];
    const float* kv_w      = (const float*)d_in[8];
    const float* kv_b      = (const float*)d_in[9];

    float* attn_out = (float*)d_ws;  // 64*256 floats = 64 KB
    float* y        = (float*)d_out;

    attn_vec_kernel<<<Bc, 512, 0, stream>>>(cond_emb, in_proj_w, in_proj_b,
                                            out_w, out_b, kv_w, kv_b, attn_out);

    // 16,777,216 float4 total = 2048 blocks x 256 threads x 32 iters.
    add_broadcast_kernel<<<2048, 256, 0, stream>>>(
        (const v4f*)x, attn_out, (v4f*)y);
}